// Round 3
// baseline (691.546 us; speedup 1.0000x reference)
//
#include <hip/hip_runtime.h>
#include <stdint.h>
#include <stddef.h>

// Problem constants
#define BATCH 4
#define SEQ   2048
#define EDIM  2048
#define NH    16
#define HD    128
#define MTOT  (BATCH*SEQ)   // 8192

// softmax scale folded into Q at GEMM1 epilogue: 1/sqrt(128) * log2(e)
#define QSCALE (0.08838834764831845f * 1.4426950408889634f)

typedef __bf16 bf16_t;
typedef __attribute__((ext_vector_type(8))) __bf16 bf16x8;
typedef __attribute__((ext_vector_type(4))) __bf16 bf16x4;
typedef __attribute__((ext_vector_type(4))) float f32x4;
typedef __attribute__((ext_vector_type(16))) float f32x16;
typedef __attribute__((ext_vector_type(2))) unsigned int uint32x2;

// async global->LDS, 16B per lane. LDS dest must be wave-uniform-base + lane*16.
#define GLD16(l, g) __builtin_amdgcn_global_load_lds( \
    (const uint32_t __attribute__((address_space(1)))*)(g), \
    (uint32_t __attribute__((address_space(3)))*)(l), 16, 0, 0)

#define RAW_BARRIER()  asm volatile("s_barrier" ::: "memory")
#define WAITCNT_VM(n)  asm volatile("s_waitcnt vmcnt(" #n ")" ::: "memory")

// ---------------------------------------------------------------------------
// fp32 -> bf16 cast, 4 elements/thread
// ---------------------------------------------------------------------------
__global__ void cast_bf16_kernel(const float* __restrict__ in,
                                 bf16_t* __restrict__ out, int n4) {
    int i = blockIdx.x * blockDim.x + threadIdx.x;
    if (i < n4) {
        float4 v = ((const float4*)in)[i];
        bf16x4 o = { (__bf16)v.x, (__bf16)v.y, (__bf16)v.z, (__bf16)v.w };
        ((bf16x4*)out)[i] = o;
    }
}

// ---------------------------------------------------------------------------
// NT GEMM, 256x256 tile, BK=64, 512 threads (8 waves 2Mx4N, 128x64 per wave),
// phase-interleaved schedule with counted vmcnt (T2+T3+T4+T5 stack).
//
// LDS: 2 K-tile double buffers for A and B, [256][64] bf16 each, 8-el-chunk
// XOR swizzle slot(row,c) <- G[row][c ^ (row&7)].  128 KiB total, 1 blk/CU.
//
// Half-tile definition matches CONSUMPTION order, not contiguous rows:
//   A-half h = rows with bit6==h   (quadrant m-halves: all waves read half0
//              in phases 1-2, half1 in phases 3-4)
//   B-half h = rows with bit5==h   (per-wave n-halves: half0 in phases 1&4,
//              half1 in phases 2-3)
// Each half-tile = 128 rows x 64 cols = 16 KiB = 2 GLD16/thread.
//
// Per K-tile, 4 phases (quadrant (MB,NB) of the wave's 8x4 frag grid):
//   p1 (0,0): read A0 frags(8) + B0 frags(4); stage A0(t+1); vm(4); BAR;
//             16 MFMA; BAR
//   p2 (0,1): read B1 frags(4);               stage B0(t+1); vm(4); BAR;
//             16 MFMA; BAR
//   p3 (1,1): read A1 frags(8);               stage B1(t+1);        BAR;
//             16 MFMA; BAR
//   p4 (1,0): (b[0..1] still in regs);        stage A1(t+1); vm(4); BAR;
//             16 MFMA; BAR
// vmcnt ledger (2 loads/half-tile, stage order A0,B0,B1,A1):
//   before p1 reads: prev-p4 vm(4) retired A0,B0 of tile t      (8 -> 4)
//   p1 vm(4): outstanding {B1,A1,newA0}=6 -> retires B1(t)      (p2 reads)
//   p2 vm(4): outstanding {A1,newA0,newB0}=6 -> retires A1(t)   (p3 reads)
//   p4 vm(4): outstanding {newA0,newB0,newB1,newA1}=8 -> retires
//             A0,B0(t+1)                                        (next p1)
// Never vmcnt(0) in the loop; prologue (stage tile0 + vm(4) + barrier)
// reproduces the p4-tail invariant exactly. Last-iter stages wrap to tile 0
// into the dead buffer (never read). Spills (if any) only make the counted
// waits stricter (extra VMEM ops age ahead of the targets), never weaker.
//
// Grid: 1D nwg = (M/256)*(N/256), XCD-chunked swizzle (nwg%8==0 for both
// 768 and 256): each XCD gets contiguous swz range = few weight-panel
// columns (3 MB <= 4 MiB XCD L2).
//
// EPI=0: route to q/k/v buffers (q,k: [bh][s][d], Q pre-scaled; v: [bh][d][s])
// EPI=1: fp32 out + bias
// ---------------------------------------------------------------------------
#define STAGE_A(dst, src, bm_, k0_, h) do { \
  _Pragma("unroll") \
  for (int i_ = 0; i_ < 2; i_++) { \
    int idx_ = i_*512 + tid; \
    int lr_ = idx_ >> 3, c_ = idx_ & 7; \
    int gr_ = (lr_ & 63) + ((lr_ & 64) << 1) + (h)*64; \
    GLD16(&(dst)[gr_*64 + c_*8], \
          (src) + ((bm_) + gr_)*(long)K + (k0_) + ((c_ ^ (gr_ & 7)) * 8)); \
  } } while (0)

#define STAGE_B(dst, src, bn_, k0_, h) do { \
  _Pragma("unroll") \
  for (int i_ = 0; i_ < 2; i_++) { \
    int idx_ = i_*512 + tid; \
    int lr_ = idx_ >> 3, c_ = idx_ & 7; \
    int gr_ = (lr_ & 31) + ((lr_ >> 5) << 6) + (h)*32; \
    GLD16(&(dst)[gr_*64 + c_*8], \
          (src) + ((bn_) + gr_)*(long)K + (k0_) + ((c_ ^ (gr_ & 7)) * 8)); \
  } } while (0)

#define READ_A(MB) do { \
  _Pragma("unroll") for (int mt_ = 0; mt_ < 4; mt_++) \
  _Pragma("unroll") for (int kk_ = 0; kk_ < 2; kk_++) \
    a[mt_][kk_] = *(const bf16x8*)&Ac[(wm + (MB)*64 + mt_*16 + l15)*64 + \
                                      (((kk_*4 + quad) ^ (l15 & 7)) * 8)]; } while (0)

#define READ_B(NB) do { \
  _Pragma("unroll") for (int nt_ = 0; nt_ < 2; nt_++) \
  _Pragma("unroll") for (int kk_ = 0; kk_ < 2; kk_++) \
    b[(NB)*2 + nt_][kk_] = *(const bf16x8*)&Bc[(wn + (NB)*32 + nt_*16 + l15)*64 + \
                                               (((kk_*4 + quad) ^ (l15 & 7)) * 8)]; } while (0)

#define MFMA_Q(MB, NB) do { \
  __builtin_amdgcn_s_setprio(1); \
  _Pragma("unroll") for (int mt_ = 0; mt_ < 4; mt_++) \
  _Pragma("unroll") for (int nt_ = 0; nt_ < 2; nt_++) \
  _Pragma("unroll") for (int kk_ = 0; kk_ < 2; kk_++) \
    acc[(MB)*4 + mt_][(NB)*2 + nt_] = __builtin_amdgcn_mfma_f32_16x16x32_bf16( \
        a[mt_][kk_], b[(NB)*2 + nt_][kk_], acc[(MB)*4 + mt_][(NB)*2 + nt_], 0, 0, 0); \
  __builtin_amdgcn_s_setprio(0); } while (0)

template<int EPI>
__global__ __launch_bounds__(512, 2)
void gemm_nt(const bf16_t* __restrict__ A, const bf16_t* __restrict__ B,
             int M, int N, int K,
             float* __restrict__ outf, const float* __restrict__ bias,
             bf16_t* __restrict__ qb, bf16_t* __restrict__ kb,
             bf16_t* __restrict__ vb)
{
    __shared__ bf16_t SA[2][256*64];
    __shared__ bf16_t SB[2][256*64];
    const int tid  = threadIdx.x;
    const int lane = tid & 63;
    const int l15  = lane & 15;
    const int quad = lane >> 4;
    const int wave = tid >> 6;
    const int wm = (wave >> 2) * 128;   // 2 m-groups of waves
    const int wn = (wave & 3) * 64;     // 4 n-groups

    // XCD-chunked block swizzle (nwg % 8 == 0 for our shapes)
    const int nbx = M >> 8;
    const int cpx = gridDim.x >> 3;
    const int bid = blockIdx.x;
    const int swz = (bid & 7) * cpx + (bid >> 3);
    const long bm = (long)(swz % nbx) * 256;
    const long bn = (long)(swz / nbx) * 256;

    f32x4 acc[8][4] = {};
    bf16x8 a[4][2], b[4][2];

    const int NT = K >> 6;

    // prologue: tile 0 -> buf 0, order A0,B0,B1,A1; vm(4) = A0,B0 landed
    STAGE_A(SA[0], A, bm, 0, 0);
    STAGE_B(SB[0], B, bn, 0, 0);
    STAGE_B(SB[0], B, bn, 0, 1);
    STAGE_A(SA[0], A, bm, 0, 1);
    WAITCNT_VM(4);
    RAW_BARRIER();

    for (int t = 0; t < NT; t++) {
        bf16_t* const Ac = SA[t & 1];
        bf16_t* const Bc = SB[t & 1];
        bf16_t* const An = SA[(t & 1) ^ 1];
        bf16_t* const Bn = SB[(t & 1) ^ 1];
        const long kn = (t + 1 == NT) ? 0 : (long)(t + 1) * 64;

        // p1: quadrant (0,0)
        READ_A(0); READ_B(0);
        STAGE_A(An, A, bm, kn, 0);
        WAITCNT_VM(4);
        RAW_BARRIER();
        MFMA_Q(0, 0);
        RAW_BARRIER();
        // p2: quadrant (0,1)
        READ_B(1);
        STAGE_B(Bn, B, bn, kn, 0);
        WAITCNT_VM(4);
        RAW_BARRIER();
        MFMA_Q(0, 1);
        RAW_BARRIER();
        // p3: quadrant (1,1)
        READ_A(1);
        STAGE_B(Bn, B, bn, kn, 1);
        RAW_BARRIER();
        MFMA_Q(1, 1);
        RAW_BARRIER();
        // p4: quadrant (1,0)  (b[0..1] still live in regs)
        STAGE_A(An, A, bm, kn, 1);
        WAITCNT_VM(4);
        RAW_BARRIER();
        MFMA_Q(1, 0);
        RAW_BARRIER();
    }

    if (EPI == 0) {
        // qkv routing epilogue. which uniform per block (256 | 2048);
        // h uniform per (wave,nt) (64-col strip within a 128 block).
#pragma unroll
        for (int nt = 0; nt < 4; nt++) {
            int colg = (int)bn + wn + nt*16 + l15;
            int which = colg >> 11;
            int e = colg & 2047;
            int h = e >> 7, d = e & 127;
#pragma unroll
            for (int mt = 0; mt < 8; mt++) {
#pragma unroll
                for (int r = 0; r < 4; r++) {
                    int rowg = (int)bm + wm + mt*16 + quad*4 + r;
                    int bb = rowg >> 11, s = rowg & 2047;
                    long bh = (long)bb*NH + h;
                    if (which == 0)
                        qb[(bh*SEQ + s)*HD + d] = (__bf16)(acc[mt][nt][r] * QSCALE);
                    else if (which == 1)
                        kb[(bh*SEQ + s)*HD + d] = (__bf16)acc[mt][nt][r];
                    else
                        vb[(bh*HD + d)*SEQ + s] = (__bf16)acc[mt][nt][r];
                }
            }
        }
    } else {
#pragma unroll
        for (int nt = 0; nt < 4; nt++) {
            int colg = (int)bn + wn + nt*16 + l15;
            float bv = bias[colg];
#pragma unroll
            for (int mt = 0; mt < 8; mt++)
#pragma unroll
                for (int r = 0; r < 4; r++) {
                    int rowg = (int)bm + wm + mt*16 + quad*4 + r;
                    outf[(long)rowg*EDIM + colg] = acc[mt][nt][r] + bv;
                }
        }
    }
}

// ---------------------------------------------------------------------------
// In-register softmax helpers (T12). Use the BUILTIN (not raw asm): the
// permlane family has VALU-write->read wait-state hazards the compiler must
// model; raw asm hid them (round-1 failure: run-varying absmax 7e-2/468).
// Semantics: r[0][l] = l<32 ? x[l] : y[l-32];  r[1][l] = l<32 ? x[l+32] : y[l].
// ---------------------------------------------------------------------------
__device__ __forceinline__ void pswap(uint32_t& x, uint32_t& y) {
    uint32x2 r = __builtin_amdgcn_permlane32_swap(x, y, false, false);
    x = r[0]; y = r[1];
}
__device__ __forceinline__ uint32_t pkbf16(float a, float b) {
    union { uint32_t u; __bf16 h[2]; } w;
    w.h[0] = (__bf16)a; w.h[1] = (__bf16)b;
    return w.u;
}
// combine with the partner lane (lane ^ 32, same q column)
__device__ __forceinline__ float xswap_max(float v) {
    union { float f; uint32_t u; } a, b;
    a.f = v; b.f = v;
    pswap(a.u, b.u);
    return fmaxf(a.f, b.f);
}
__device__ __forceinline__ float xswap_add(float v) {
    union { float f; uint32_t u; } a, b;
    a.f = v; b.f = v;
    pswap(a.u, b.u);
    return a.f + b.f;
}

// Build one PV B-fragment (16 kv x 32 q slice) from the 32x32 QK accumulator.
// Input (C-layout, m74/m101): lane holds col q = lane&31; reg r holds row
// (r&3) + 4*(lane>>5) + 8*(r>>2).  Output (B-frag layout): lane holds
// q = lane&31, elements j=0..7 at row = 16*(B/8) + (lane>>5)*8 + j.
// One permlane32_swap fills two output words (j{0,1}&j{4,5}; j{2,3}&j{6,7}).
template<int B>
__device__ __forceinline__ bf16x8 mkfrag(f32x16 p) {
    uint32_t w0 = pkbf16(p[B+0], p[B+1]);
    uint32_t w2 = pkbf16(p[B+4], p[B+5]);
    pswap(w0, w2);
    uint32_t w1 = pkbf16(p[B+2], p[B+3]);
    uint32_t w3 = pkbf16(p[B+6], p[B+7]);
    pswap(w1, w3);
    union { uint32_t u[4]; bf16x8 v; } r;
    r.u[0] = w0; r.u[1] = w1; r.u[2] = w2; r.u[3] = w3;
    return r.v;
}

// ---------------------------------------------------------------------------
// Flash attention v5: 8-wave 32x32 swapped-QK^T, fully in-register softmax.
// One block = 256 q rows of one (b,h); 8 waves x 32 rows; KV-tile = 64.
// QK^T computed as mfma(K, Q) -> lane owns q = lane&31 (full kv extent split
// between lane and lane^32): row max/sum = in-lane tree + 1 permlane32_swap.
// P never touches LDS: bf16 PV fragments built via pack + permlane32_swap.
// PV computed as mfma(V^T, P) -> O keeps q lane-local; rescale is a
// lane-scalar multiply. Same transform converts O to row-major 16B stores.
// LDS 64 KB (K0|K1|V0|V1 double-buffered), Q in registers. 2 barriers/tile,
// counted vmcnt(4) so prefetch loads stay in flight across B1.
// Grid 512 = bh(64) x qtile(8); bh&7 = XCD -> 8 heads/XCD = 4 MB K+V = L2.
// ---------------------------------------------------------------------------
__global__ __launch_bounds__(512, 2)
void attn_kernel(const bf16_t* __restrict__ qb, const bf16_t* __restrict__ kb,
                 const bf16_t* __restrict__ vb, bf16_t* __restrict__ ob)
{
    __shared__ bf16_t SM[32768];        // 64 KB
    bf16_t* const K0 = SM;              // [64 s][128 d]  16 KB each
    bf16_t* const K1 = SM + 8192;
    bf16_t* const V0 = SM + 16384;      // [128 d][64 s]
    bf16_t* const V1 = SM + 24576;

    const int tid  = threadIdx.x;
    const int lane = tid & 63;
    const int l31  = lane & 31;
    const int l15  = lane & 15;
    const int l7   = lane & 7;
    const int hi   = lane >> 5;
    const int warp = tid >> 6;

    const int bh = blockIdx.x & 63;     // bh&7 = XCD: all 8 q-tiles same XCD
    const int q0 = (blockIdx.x >> 6) * 256;
    const int b  = bh >> 4;
    const int h  = bh & 15;

    const bf16_t* kg0 = kb + (long)bh*SEQ*HD;
    const bf16_t* vg0 = vb + (long)bh*HD*SEQ;

    // ---- Q direct to registers (B-frags: lane q = l31, k = hi*8+j) ----
    bf16x8 qf[8];
    {
        const bf16_t* qg = qb + ((long)bh*SEQ + q0 + warp*32 + l31)*HD + hi*8;
#pragma unroll
        for (int ds = 0; ds < 8; ds++)
            qf[ds] = *(const bf16x8*)(qg + ds*16);
    }

    // ---- stage tile 0 (K: 64x128 rows swz ^row&15; V: 128x64 swz ^row&7) --
#pragma unroll
    for (int i = 0; i < 2; i++) {
        int lin = i*4096 + tid*8;
        { int row = lin >> 7, c = (lin >> 3) & 15;
          GLD16(&K0[lin], kg0 + (long)row*HD + ((c ^ (row & 15)) * 8)); }
        { int row = lin >> 6, c = (lin >> 3) & 7;
          GLD16(&V0[lin], vg0 + (long)row*SEQ + ((c ^ (row & 7)) * 8)); }
    }

    f32x16 oacc[4] = {};                // O^T: lane q = l31, d = crow(reg)+32*dblk
    float m = -1e30f, lsum = 0.f;

    const int NT = SEQ / 64;             // 32
    for (int t = 0; t < NT; t++) {
        bf16_t* const Kc = (t & 1) ? K1 : K0;
        bf16_t* const Vc = (t & 1) ? V1 : V0;
        bf16_t* const Kn = (t & 1) ? K0 : K1;
        bf16_t* const Vn = (t & 1) ? V0 : V1;

        RAW_BARRIER();                   // B1: all waves done compute t-1
        {   // prefetch tile t+1 (wrap on last iter: harmless reload)
            int tn = (t + 1 == NT) ? 0 : t + 1;
            const bf16_t* kg = kg0 + (long)tn*64*HD;
            const bf16_t* vg = vg0 + tn*64;
#pragma unroll
            for (int i = 0; i < 2; i++) {
                int lin = i*4096 + tid*8;
                { int row = lin >> 7, c = (lin >> 3) & 15;
                  GLD16(&Kn[lin], kg + (long)row*HD + ((c ^ (row & 15)) * 8)); }
                { int row = lin >> 6, c = (lin >> 3) & 7;
                  GLD16(&Vn[lin], vg + (long)row*SEQ + ((c ^ (row & 7)) * 8)); }
            }
        }
        WAITCNT_VM(4);                   // my 4 tile-t loads landed
        RAW_BARRIER();                   // B2: everyone's tile-t data in LDS

        // ---- S^T = K Q^T: p0 = kv 0..31, p1 = kv 32..63 (col q per lane) --
        f32x16 p0 = {}, p1 = {};
        __builtin_amdgcn_s_setprio(1);
#pragma unroll
        for (int ds = 0; ds < 8; ds++) {
            const int sc = ((ds*2 + hi) ^ l15) * 8;
            bf16x8 kf0 = *(const bf16x8*)&Kc[l31*128 + sc];
            bf16x8 kf1 = *(const bf16x8*)&Kc[(32 + l31)*128 + sc];
            p0 = __builtin_amdgcn_mfma_f32_32x32x16_bf16(kf0, qf[ds], p0, 0, 0, 0);
            p1 = __builtin_amdgcn_mfma_f32_32x32x16_bf16(kf1, qf[ds], p1, 0, 0, 0);
        }
        __builtin_amdgcn_s_setprio(0);

        // ---- softmax: in-lane trees + partner exchange, all in-register ----
        float mx;
        {
            float tm[8];
#pragma unroll
            for (int r = 0; r < 8; r++)
                tm[r] = fmaxf(fmaxf(p0[r], p0[r+8]), fmaxf(p1[r], p1[r+8]));
#pragma unroll
            for (int s2 = 4; s2 > 0; s2 >>= 1)
#pragma unroll
                for (int r = 0; r < s2; r++) tm[r] = fmaxf(tm[r], tm[r+s2]);
            mx = xswap_max(tm[0]);
        }
        float mo = m;
        float mn = fmaxf(mo, mx);
        m = mn;
        if (__any(mn > mo)) {            // guarded rescale (lane-scalar factor)
            float av = exp2f(mo - mn);
            lsum *= av;
#pragma unroll
            for (int d = 0; d < 4; d++)
#pragma unroll
                for (int r = 0; r < 16; r++) oacc[d][r] *= av;
        }
#pragma unroll
        for (int r = 0; r < 16; r++) p0[r] = exp2f(p0[r] - mn);
#pragma unroll
        for (int r = 0; r < 16; r++) p1[r] = exp2f(p1[r] - mn);
        {
            float ts[8];
#pragma unroll
            for (int r = 0; r < 8; r++)
                ts[r] = (p0[r] + p0[r+8]) + (p1[r] + p1[r+8]);
#pragma unroll
            for (int s2 = 4; s2 > 0; s2 >>= 1)
#pragma unroll
                for (int r = 0; r < s2; r++) ts[r] += ts[r+s2];
            lsum += xswap_add(ts[0]);
        }

        // ---- P -> bf16 fragments in-register, then O^T += V^T P^T ----
        bf16x8 pf0 = mkfrag<0>(p0);      // kv  0..15
        bf16x8 pf1 = mkfrag<8>(p0);      // kv 16..31
        bf16x8 pf2 = mkfrag<0>(p1);      // kv 32..47
        bf16x8 pf3 = mkfrag<8>(p1);      // kv 48..63
        __builtin_amdgcn_s_setprio(1);
#pragma unroll
        for (int d = 0; d < 4; d++) {
            bf16x8 vf0 = *(const bf16x8*)&Vc[(d*32 + l31)*64 + (((0 + hi) ^ l7) * 8)];
            oacc[d] = __builtin_amdgcn_mfma_f32_32x32x16_bf16(vf0, pf0, oacc[d], 0, 0, 0);
            bf16x8 vf1 = *(const bf16x8*)&Vc[(d*32 + l31)*64 + (((2 + hi) ^ l7) * 8)];
            oacc[d] = __builtin_amdgcn_mfma_f32_32x32x16_bf16(vf1, pf1, oacc[d], 0, 0, 0);
            bf16x8 vf2 = *(const bf16x8*)&Vc[(d*32 + l31)*64 + (((4 + hi) ^ l7) * 8)];
            oacc[d] = __builtin_amdgcn_mfma_f32_32x32x16_bf16(vf2, pf2, oacc[d], 0, 0, 0);
            bf16x8 vf3 = *(const bf16x8*)&Vc[(d*32 + l31)*64 + (((6 + hi) ^ l7) * 8)];
            oacc[d] = __builtin_amdgcn_mfma_f32_32x32x16_bf16(vf3, pf3, oacc[d], 0, 0, 0);
        }
        __builtin_amdgcn_s_setprio(0);
    }

    // ---- epilogue: O/l, transform to row-major frags, 16B coalesced stores -
    {
        float inv = 1.0f / lsum;
        long obase = ((long)b*SEQ + q0 + warp*32 + l31)*EDIM + h*HD + hi*8;
#pragma unroll
        for (int d = 0; d < 4; d++) {
            f32x16 o;
#pragma unroll
            for (int r = 0; r < 16; r++) o[r] = oacc[d][r] * inv;
            bf16x8 f0 = mkfrag<0>(o);    // d-cols 32d+16*0+hi*8 .. +7
            bf16x8 f1 = mkfrag<8>(o);    // d-cols 32d+16*1+hi*8 .. +7
            *(bf16x8*)&ob[obase + d*32]      = f0;
            *(bf16x8*)&ob[obase + d*32 + 16] = f1;
        }
    }
}

// ---------------------------------------------------------------------------
extern "C" void kernel_launch(void* const* d_in, const int* in_sizes, int n_in,
                              void* d_out, int out_size, void* d_ws, size_t ws_size,
                              hipStream_t stream) {
    const float* x    = (const float*)d_in[0];
    const float* wqkv = (const float*)d_in[1];
    const float* wout = (const float*)d_in[2];
    const float* bout = (const float*)d_in[3];
    float* out = (float*)d_out;

    char* w = (char*)d_ws;
    bf16_t* xb    = (bf16_t*)w; w += (size_t)MTOT*EDIM*2;     // 33.5 MB
    bf16_t* wqkvb = (bf16_t*)w; w += (size_t)3*EDIM*EDIM*2;   // 25.2 MB
    bf16_t* woutb = (bf16_t*)w; w += (size_t)EDIM*EDIM*2;     //  8.4 MB
    bf16_t* qbuf  = (bf16_t*)w; w += (size_t)MTOT*EDIM*2;     // 33.5 MB  [bh][s][d]
    bf16_t* kbuf  = (bf16_t*)w; w += (size_t)MTOT*EDIM*2;     // 33.5 MB  [bh][s][d]
    bf16_t* vbuf  = (bf16_t*)w; w += (size_t)MTOT*EDIM*2;     // 33.5 MB  [bh][d][s]
    bf16_t* attnb = (bf16_t*)w; w += (size_t)MTOT*EDIM*2;     // 33.5 MB  [b][s][e]

    cast_bf16_kernel<<<MTOT*EDIM/1024, 256, 0, stream>>>(x, xb, MTOT*EDIM/4);
    cast_bf16_kernel<<<3*EDIM*EDIM/1024, 256, 0, stream>>>(wqkv, wqkvb, 3*EDIM*EDIM/4);
    cast_bf16_kernel<<<EDIM*EDIM/1024, 256, 0, stream>>>(wout, woutb, EDIM*EDIM/4);

    gemm_nt<0><<<dim3((MTOT/256)*(3*EDIM/256)), 512, 0, stream>>>(
        xb, wqkvb, MTOT, 3*EDIM, EDIM, nullptr, nullptr, qbuf, kbuf, vbuf);

    attn_kernel<<<dim3(512), 512, 0, stream>>>(qbuf, kbuf, vbuf, attnb);

    gemm_nt<1><<<dim3((MTOT/256)*(EDIM/256)), 512, 0, stream>>>(
        attnb, woutb, MTOT, EDIM, EDIM, out, bout, nullptr, nullptr, nullptr);
}

// Round 4
// 627.209 us; speedup vs baseline: 1.1026x; 1.1026x over previous
//
#include <hip/hip_runtime.h>
#include <stdint.h>
#include <stddef.h>

// Problem constants
#define BATCH 4
#define SEQ   2048
#define EDIM  2048
#define NH    16
#define HD    128
#define MTOT  (BATCH*SEQ)   // 8192

// softmax scale folded into Q at GEMM1 epilogue: 1/sqrt(128) * log2(e)
#define QSCALE (0.08838834764831845f * 1.4426950408889634f)

typedef __bf16 bf16_t;
typedef __attribute__((ext_vector_type(8))) __bf16 bf16x8;
typedef __attribute__((ext_vector_type(4))) __bf16 bf16x4;
typedef __attribute__((ext_vector_type(4))) float f32x4;
typedef __attribute__((ext_vector_type(16))) float f32x16;
typedef __attribute__((ext_vector_type(2))) unsigned int uint32x2;

// async global->LDS, 16B per lane. LDS dest must be wave-uniform-base + lane*16.
#define GLD16(l, g) __builtin_amdgcn_global_load_lds( \
    (const uint32_t __attribute__((address_space(1)))*)(g), \
    (uint32_t __attribute__((address_space(3)))*)(l), 16, 0, 0)

#define RAW_BARRIER()  asm volatile("s_barrier" ::: "memory")
#define WAITCNT_VM(n)  asm volatile("s_waitcnt vmcnt(" #n ")" ::: "memory")

// ---------------------------------------------------------------------------
// fp32 -> bf16 cast, 4 elements/thread
// ---------------------------------------------------------------------------
__global__ void cast_bf16_kernel(const float* __restrict__ in,
                                 bf16_t* __restrict__ out, int n4) {
    int i = blockIdx.x * blockDim.x + threadIdx.x;
    if (i < n4) {
        float4 v = ((const float4*)in)[i];
        bf16x4 o = { (__bf16)v.x, (__bf16)v.y, (__bf16)v.z, (__bf16)v.w };
        ((bf16x4*)out)[i] = o;
    }
}

// ---------------------------------------------------------------------------
// NT GEMM, 256x256 tile, BK=64, 512 threads (8 waves 2Mx4N, 128x64 per wave),
// 4-phase counted-vmcnt schedule, uniform 3-phase prefetch distance.
//
// ROUND-3 POST-MORTEM FIXES:
// (a) XCD m-panel pinning: xcd = bid&7 owns MC=4 consecutive m-tiles (4 MB of
//     A resident in its 4 MB L2), sweeps all n with m-inner order. Round-3's
//     chunked swizzle streamed ALL of A through every XCD L2: FETCH 212->418MB.
// (b) Wait ledger: 3 waits + 4 barriers per K-tile, every wait targets loads
//     issued exactly 3 phases earlier (round-3 had a 2-phase weak link + 8
//     barriers -> exposed L2-miss latency at 1 blk/CU).
//
// LDS: 2 K-tile double buffers for A and B, [256][64] bf16, 8-el-chunk XOR
// swizzle slot(row,c) <- G[row][c ^ (row&7)].  128 KiB total, 1 blk/CU.
// Half-tiles (16 KiB = 2 GLD16/thread), defined by CONSUMPTION:
//   A-half h = rows with bit6==h ; B-half h = rows with bit5==h.
//
// Phases (quadrant (MB,NB) of each wave's 8x4 frag grid); B0,B1 frags are
// HELD IN REGS across the tile (reads: p1{A0,B0} p2{B1} p3{A1} p4{}):
//   p1 (0,0): READ A0,B0; stage A0',B0'; vm(6); BAR; MFMA
//   p2 (0,1): READ B1;    stage B1';     vm(6); BAR; MFMA
//   p3 (1,1): READ A1;    stage A1';            BAR; MFMA
//   p4 (1,0): (regs only);               vm(4); BAR; MFMA
// Per-wave ledger (2 loads/half, 4 at p1), steady state:
//   p1 wait: outstanding {B1(t),A1(t),A0'B0'}=8 -> vm(6) retires B1(t)   [d3]
//   p2 wait: outstanding {A1(t),A0'B0',B1'}=8  -> vm(6) retires A1(t)    [d3]
//   p4 wait: outstanding {A0'B0',B1',A1'}=8    -> vm(4) retires A0',B0'  [d3]
// Single barrier per phase: stages go to the OPPOSITE buffer, so end-of-phase
// barriers protect nothing; the begin-barrier after each wait provides
// cross-wave visibility for the next phase's ds_reads. Prologue (stage
// A0,B0,B1,A1; vm(4); BAR) reproduces the steady-state invariant exactly.
// Spills (if any) only make counted waits stricter, never weaker.
//
// EPI=0: route to q/k/v buffers (q,k: [bh][s][d], Q pre-scaled; v: [bh][d][s])
// EPI=1: fp32 out + bias
// ---------------------------------------------------------------------------
#define STAGE_A(dst, src, bm_, k0_, h) do { \
  _Pragma("unroll") \
  for (int i_ = 0; i_ < 2; i_++) { \
    int idx_ = i_*512 + tid; \
    int lr_ = idx_ >> 3, c_ = idx_ & 7; \
    int gr_ = (lr_ & 63) + ((lr_ & 64) << 1) + (h)*64; \
    GLD16(&(dst)[gr_*64 + c_*8], \
          (src) + ((bm_) + gr_)*(long)K + (k0_) + ((c_ ^ (gr_ & 7)) * 8)); \
  } } while (0)

#define STAGE_B(dst, src, bn_, k0_, h) do { \
  _Pragma("unroll") \
  for (int i_ = 0; i_ < 2; i_++) { \
    int idx_ = i_*512 + tid; \
    int lr_ = idx_ >> 3, c_ = idx_ & 7; \
    int gr_ = (lr_ & 31) + ((lr_ >> 5) << 6) + (h)*32; \
    GLD16(&(dst)[gr_*64 + c_*8], \
          (src) + ((bn_) + gr_)*(long)K + (k0_) + ((c_ ^ (gr_ & 7)) * 8)); \
  } } while (0)

#define READ_A(MB) do { \
  _Pragma("unroll") for (int mt_ = 0; mt_ < 4; mt_++) \
  _Pragma("unroll") for (int kk_ = 0; kk_ < 2; kk_++) \
    a[mt_][kk_] = *(const bf16x8*)&Ac[(wm + (MB)*64 + mt_*16 + l15)*64 + \
                                      (((kk_*4 + quad) ^ (l15 & 7)) * 8)]; } while (0)

#define READ_B(arr, NB) do { \
  _Pragma("unroll") for (int nt_ = 0; nt_ < 2; nt_++) \
  _Pragma("unroll") for (int kk_ = 0; kk_ < 2; kk_++) \
    arr[nt_][kk_] = *(const bf16x8*)&Bc[(wn + (NB)*32 + nt_*16 + l15)*64 + \
                                        (((kk_*4 + quad) ^ (l15 & 7)) * 8)]; } while (0)

#define MFMA_Q(MB, NB, arr) do { \
  __builtin_amdgcn_s_setprio(1); \
  _Pragma("unroll") for (int mt_ = 0; mt_ < 4; mt_++) \
  _Pragma("unroll") for (int nt_ = 0; nt_ < 2; nt_++) \
  _Pragma("unroll") for (int kk_ = 0; kk_ < 2; kk_++) \
    acc[(MB)*4 + mt_][(NB)*2 + nt_] = __builtin_amdgcn_mfma_f32_16x16x32_bf16( \
        a[mt_][kk_], arr[nt_][kk_], acc[(MB)*4 + mt_][(NB)*2 + nt_], 0, 0, 0); \
  __builtin_amdgcn_s_setprio(0); } while (0)

template<int EPI>
__global__ __launch_bounds__(512, 2)
void gemm_nt(const bf16_t* __restrict__ A, const bf16_t* __restrict__ B,
             int M, int N, int K,
             float* __restrict__ outf, const float* __restrict__ bias,
             bf16_t* __restrict__ qb, bf16_t* __restrict__ kb,
             bf16_t* __restrict__ vb)
{
    __shared__ bf16_t SA[2][256*64];
    __shared__ bf16_t SB[2][256*64];
    const int tid  = threadIdx.x;
    const int lane = tid & 63;
    const int l15  = lane & 15;
    const int quad = lane >> 4;
    const int wave = tid >> 6;
    const int wm = (wave >> 2) * 128;   // 2 m-groups of waves
    const int wn = (wave & 3) * 64;     // 4 n-groups

    // XCD m-panel pinning: xcd owns MC consecutive m-tiles, m-inner order
    // (B panel reused by the MC blocks back-to-back; A stays L2-resident).
    const int MC  = (M >> 8) >> 3;      // m-tiles per XCD (4 for M=8192)
    const int xcd = blockIdx.x & 7;
    const int j   = blockIdx.x >> 3;
    const long bm = (long)(xcd * MC + (j % MC)) * 256;
    const long bn = (long)(j / MC) * 256;

    f32x4 acc[8][4] = {};
    bf16x8 a[4][2], b0[2][2], b1[2][2];

    const int NT = K >> 6;

    // prologue: tile 0 -> buf 0, issue order A0,B0,B1,A1; vm(4) = A0,B0 landed
    STAGE_A(SA[0], A, bm, 0, 0);
    STAGE_B(SB[0], B, bn, 0, 0);
    STAGE_B(SB[0], B, bn, 0, 1);
    STAGE_A(SA[0], A, bm, 0, 1);
    WAITCNT_VM(4);
    RAW_BARRIER();

    for (int t = 0; t < NT; t++) {
        bf16_t* const Ac = SA[t & 1];
        bf16_t* const Bc = SB[t & 1];
        bf16_t* const An = SA[(t & 1) ^ 1];
        bf16_t* const Bn = SB[(t & 1) ^ 1];
        const long kn = (t + 1 == NT) ? 0 : (long)(t + 1) * 64;

        // p1 (0,0)
        READ_A(0); READ_B(b0, 0);
        STAGE_A(An, A, bm, kn, 0);
        STAGE_B(Bn, B, bn, kn, 0);
        WAITCNT_VM(6);
        RAW_BARRIER();
        MFMA_Q(0, 0, b0);
        // p2 (0,1)
        READ_B(b1, 1);
        STAGE_B(Bn, B, bn, kn, 1);
        WAITCNT_VM(6);
        RAW_BARRIER();
        MFMA_Q(0, 1, b1);
        // p3 (1,1)
        READ_A(1);
        STAGE_A(An, A, bm, kn, 1);
        RAW_BARRIER();
        MFMA_Q(1, 1, b1);
        // p4 (1,0)  (a = A1 from p3, b0 held since p1)
        WAITCNT_VM(4);
        RAW_BARRIER();
        MFMA_Q(1, 0, b0);
    }

    if (EPI == 0) {
        // qkv routing epilogue. which uniform per block (256 | 2048);
        // h uniform per (wave,nt) (64-col strip within a 128 block).
#pragma unroll
        for (int nt = 0; nt < 4; nt++) {
            int colg = (int)bn + wn + nt*16 + l15;
            int which = colg >> 11;
            int e = colg & 2047;
            int h = e >> 7, d = e & 127;
#pragma unroll
            for (int mt = 0; mt < 8; mt++) {
#pragma unroll
                for (int r = 0; r < 4; r++) {
                    int rowg = (int)bm + wm + mt*16 + quad*4 + r;
                    int bb = rowg >> 11, s = rowg & 2047;
                    long bh = (long)bb*NH + h;
                    if (which == 0)
                        qb[(bh*SEQ + s)*HD + d] = (__bf16)(acc[mt][nt][r] * QSCALE);
                    else if (which == 1)
                        kb[(bh*SEQ + s)*HD + d] = (__bf16)acc[mt][nt][r];
                    else
                        vb[(bh*HD + d)*SEQ + s] = (__bf16)acc[mt][nt][r];
                }
            }
        }
    } else {
#pragma unroll
        for (int nt = 0; nt < 4; nt++) {
            int colg = (int)bn + wn + nt*16 + l15;
            float bv = bias[colg];
#pragma unroll
            for (int mt = 0; mt < 8; mt++)
#pragma unroll
                for (int r = 0; r < 4; r++) {
                    int rowg = (int)bm + wm + mt*16 + quad*4 + r;
                    outf[(long)rowg*EDIM + colg] = acc[mt][nt][r] + bv;
                }
        }
    }
}

// ---------------------------------------------------------------------------
// In-register softmax helpers (T12). Use the BUILTIN (not raw asm): the
// permlane family has VALU-write->read wait-state hazards the compiler must
// model; raw asm hid them (round-1 failure: run-varying absmax 7e-2/468).
// Semantics: r[0][l] = l<32 ? x[l] : y[l-32];  r[1][l] = l<32 ? x[l+32] : y[l].
// ---------------------------------------------------------------------------
__device__ __forceinline__ void pswap(uint32_t& x, uint32_t& y) {
    uint32x2 r = __builtin_amdgcn_permlane32_swap(x, y, false, false);
    x = r[0]; y = r[1];
}
__device__ __forceinline__ uint32_t pkbf16(float a, float b) {
    union { uint32_t u; __bf16 h[2]; } w;
    w.h[0] = (__bf16)a; w.h[1] = (__bf16)b;
    return w.u;
}
// combine with the partner lane (lane ^ 32, same q column)
__device__ __forceinline__ float xswap_max(float v) {
    union { float f; uint32_t u; } a, b;
    a.f = v; b.f = v;
    pswap(a.u, b.u);
    return fmaxf(a.f, b.f);
}
__device__ __forceinline__ float xswap_add(float v) {
    union { float f; uint32_t u; } a, b;
    a.f = v; b.f = v;
    pswap(a.u, b.u);
    return a.f + b.f;
}

// Build one PV B-fragment (16 kv x 32 q slice) from the 32x32 QK accumulator.
// Input (C-layout, m74/m101): lane holds col q = lane&31; reg r holds row
// (r&3) + 4*(lane>>5) + 8*(r>>2).  Output (B-frag layout): lane holds
// q = lane&31, elements j=0..7 at row = 16*(B/8) + (lane>>5)*8 + j.
// One permlane32_swap fills two output words (j{0,1}&j{4,5}; j{2,3}&j{6,7}).
template<int B>
__device__ __forceinline__ bf16x8 mkfrag(f32x16 p) {
    uint32_t w0 = pkbf16(p[B+0], p[B+1]);
    uint32_t w2 = pkbf16(p[B+4], p[B+5]);
    pswap(w0, w2);
    uint32_t w1 = pkbf16(p[B+2], p[B+3]);
    uint32_t w3 = pkbf16(p[B+6], p[B+7]);
    pswap(w1, w3);
    union { uint32_t u[4]; bf16x8 v; } r;
    r.u[0] = w0; r.u[1] = w1; r.u[2] = w2; r.u[3] = w3;
    return r.v;
}

// ---------------------------------------------------------------------------
// Flash attention v5: 8-wave 32x32 swapped-QK^T, fully in-register softmax.
// One block = 256 q rows of one (b,h); 8 waves x 32 rows; KV-tile = 64.
// QK^T computed as mfma(K, Q) -> lane owns q = lane&31 (full kv extent split
// between lane and lane^32): row max/sum = in-lane tree + 1 permlane32_swap.
// P never touches LDS: bf16 PV fragments built via pack + permlane32_swap.
// PV computed as mfma(V^T, P) -> O keeps q lane-local; rescale is a
// lane-scalar multiply. Same transform converts O to row-major 16B stores.
// LDS 64 KB (K0|K1|V0|V1 double-buffered), Q in registers. 2 barriers/tile,
// counted vmcnt(4) so prefetch loads stay in flight across B1.
// Grid 512 = bh(64) x qtile(8); bh&7 = XCD -> 8 heads/XCD = 4 MB K+V = L2.
// ---------------------------------------------------------------------------
__global__ __launch_bounds__(512, 2)
void attn_kernel(const bf16_t* __restrict__ qb, const bf16_t* __restrict__ kb,
                 const bf16_t* __restrict__ vb, bf16_t* __restrict__ ob)
{
    __shared__ bf16_t SM[32768];        // 64 KB
    bf16_t* const K0 = SM;              // [64 s][128 d]  16 KB each
    bf16_t* const K1 = SM + 8192;
    bf16_t* const V0 = SM + 16384;      // [128 d][64 s]
    bf16_t* const V1 = SM + 24576;

    const int tid  = threadIdx.x;
    const int lane = tid & 63;
    const int l31  = lane & 31;
    const int l15  = lane & 15;
    const int l7   = lane & 7;
    const int hi   = lane >> 5;
    const int warp = tid >> 6;

    const int bh = blockIdx.x & 63;     // bh&7 = XCD: all 8 q-tiles same XCD
    const int q0 = (blockIdx.x >> 6) * 256;
    const int b  = bh >> 4;
    const int h  = bh & 15;

    const bf16_t* kg0 = kb + (long)bh*SEQ*HD;
    const bf16_t* vg0 = vb + (long)bh*HD*SEQ;

    // ---- Q direct to registers (B-frags: lane q = l31, k = hi*8+j) ----
    bf16x8 qf[8];
    {
        const bf16_t* qg = qb + ((long)bh*SEQ + q0 + warp*32 + l31)*HD + hi*8;
#pragma unroll
        for (int ds = 0; ds < 8; ds++)
            qf[ds] = *(const bf16x8*)(qg + ds*16);
    }

    // ---- stage tile 0 (K: 64x128 rows swz ^row&15; V: 128x64 swz ^row&7) --
#pragma unroll
    for (int i = 0; i < 2; i++) {
        int lin = i*4096 + tid*8;
        { int row = lin >> 7, c = (lin >> 3) & 15;
          GLD16(&K0[lin], kg0 + (long)row*HD + ((c ^ (row & 15)) * 8)); }
        { int row = lin >> 6, c = (lin >> 3) & 7;
          GLD16(&V0[lin], vg0 + (long)row*SEQ + ((c ^ (row & 7)) * 8)); }
    }

    f32x16 oacc[4] = {};                // O^T: lane q = l31, d = crow(reg)+32*dblk
    float m = -1e30f, lsum = 0.f;

    const int NT = SEQ / 64;             // 32
    for (int t = 0; t < NT; t++) {
        bf16_t* const Kc = (t & 1) ? K1 : K0;
        bf16_t* const Vc = (t & 1) ? V1 : V0;
        bf16_t* const Kn = (t & 1) ? K0 : K1;
        bf16_t* const Vn = (t & 1) ? V0 : V1;

        RAW_BARRIER();                   // B1: all waves done compute t-1
        {   // prefetch tile t+1 (wrap on last iter: harmless reload)
            int tn = (t + 1 == NT) ? 0 : t + 1;
            const bf16_t* kg = kg0 + (long)tn*64*HD;
            const bf16_t* vg = vg0 + tn*64;
#pragma unroll
            for (int i = 0; i < 2; i++) {
                int lin = i*4096 + tid*8;
                { int row = lin >> 7, c = (lin >> 3) & 15;
                  GLD16(&Kn[lin], kg + (long)row*HD + ((c ^ (row & 15)) * 8)); }
                { int row = lin >> 6, c = (lin >> 3) & 7;
                  GLD16(&Vn[lin], vg + (long)row*SEQ + ((c ^ (row & 7)) * 8)); }
            }
        }
        WAITCNT_VM(4);                   // my 4 tile-t loads landed
        RAW_BARRIER();                   // B2: everyone's tile-t data in LDS

        // ---- S^T = K Q^T: p0 = kv 0..31, p1 = kv 32..63 (col q per lane) --
        f32x16 p0 = {}, p1 = {};
        __builtin_amdgcn_s_setprio(1);
#pragma unroll
        for (int ds = 0; ds < 8; ds++) {
            const int sc = ((ds*2 + hi) ^ l15) * 8;
            bf16x8 kf0 = *(const bf16x8*)&Kc[l31*128 + sc];
            bf16x8 kf1 = *(const bf16x8*)&Kc[(32 + l31)*128 + sc];
            p0 = __builtin_amdgcn_mfma_f32_32x32x16_bf16(kf0, qf[ds], p0, 0, 0, 0);
            p1 = __builtin_amdgcn_mfma_f32_32x32x16_bf16(kf1, qf[ds], p1, 0, 0, 0);
        }
        __builtin_amdgcn_s_setprio(0);

        // ---- softmax: in-lane trees + partner exchange, all in-register ----
        float mx;
        {
            float tm[8];
#pragma unroll
            for (int r = 0; r < 8; r++)
                tm[r] = fmaxf(fmaxf(p0[r], p0[r+8]), fmaxf(p1[r], p1[r+8]));
#pragma unroll
            for (int s2 = 4; s2 > 0; s2 >>= 1)
#pragma unroll
                for (int r = 0; r < s2; r++) tm[r] = fmaxf(tm[r], tm[r+s2]);
            mx = xswap_max(tm[0]);
        }
        float mo = m;
        float mn = fmaxf(mo, mx);
        m = mn;
        if (__any(mn > mo)) {            // guarded rescale (lane-scalar factor)
            float av = exp2f(mo - mn);
            lsum *= av;
#pragma unroll
            for (int d = 0; d < 4; d++)
#pragma unroll
                for (int r = 0; r < 16; r++) oacc[d][r] *= av;
        }
#pragma unroll
        for (int r = 0; r < 16; r++) p0[r] = exp2f(p0[r] - mn);
#pragma unroll
        for (int r = 0; r < 16; r++) p1[r] = exp2f(p1[r] - mn);
        {
            float ts[8];
#pragma unroll
            for (int r = 0; r < 8; r++)
                ts[r] = (p0[r] + p0[r+8]) + (p1[r] + p1[r+8]);
#pragma unroll
            for (int s2 = 4; s2 > 0; s2 >>= 1)
#pragma unroll
                for (int r = 0; r < s2; r++) ts[r] += ts[r+s2];
            lsum += xswap_add(ts[0]);
        }

        // ---- P -> bf16 fragments in-register, then O^T += V^T P^T ----
        bf16x8 pf0 = mkfrag<0>(p0);      // kv  0..15
        bf16x8 pf1 = mkfrag<8>(p0);      // kv 16..31
        bf16x8 pf2 = mkfrag<0>(p1);      // kv 32..47
        bf16x8 pf3 = mkfrag<8>(p1);      // kv 48..63
        __builtin_amdgcn_s_setprio(1);
#pragma unroll
        for (int d = 0; d < 4; d++) {
            bf16x8 vf0 = *(const bf16x8*)&Vc[(d*32 + l31)*64 + (((0 + hi) ^ l7) * 8)];
            oacc[d] = __builtin_amdgcn_mfma_f32_32x32x16_bf16(vf0, pf0, oacc[d], 0, 0, 0);
            bf16x8 vf1 = *(const bf16x8*)&Vc[(d*32 + l31)*64 + (((2 + hi) ^ l7) * 8)];
            oacc[d] = __builtin_amdgcn_mfma_f32_32x32x16_bf16(vf1, pf1, oacc[d], 0, 0, 0);
            bf16x8 vf2 = *(const bf16x8*)&Vc[(d*32 + l31)*64 + (((4 + hi) ^ l7) * 8)];
            oacc[d] = __builtin_amdgcn_mfma_f32_32x32x16_bf16(vf2, pf2, oacc[d], 0, 0, 0);
            bf16x8 vf3 = *(const bf16x8*)&Vc[(d*32 + l31)*64 + (((6 + hi) ^ l7) * 8)];
            oacc[d] = __builtin_amdgcn_mfma_f32_32x32x16_bf16(vf3, pf3, oacc[d], 0, 0, 0);
        }
        __builtin_amdgcn_s_setprio(0);
    }

    // ---- epilogue: O/l, transform to row-major frags, 16B coalesced stores -
    {
        float inv = 1.0f / lsum;
        long obase = ((long)b*SEQ + q0 + warp*32 + l31)*EDIM + h*HD + hi*8;
#pragma unroll
        for (int d = 0; d < 4; d++) {
            f32x16 o;
#pragma unroll
            for (int r = 0; r < 16; r++) o[r] = oacc[d][r] * inv;
            bf16x8 f0 = mkfrag<0>(o);    // d-cols 32d+16*0+hi*8 .. +7
            bf16x8 f1 = mkfrag<8>(o);    // d-cols 32d+16*1+hi*8 .. +7
            *(bf16x8*)&ob[obase + d*32]      = f0;
            *(bf16x8*)&ob[obase + d*32 + 16] = f1;
        }
    }
}

// ---------------------------------------------------------------------------
extern "C" void kernel_launch(void* const* d_in, const int* in_sizes, int n_in,
                              void* d_out, int out_size, void* d_ws, size_t ws_size,
                              hipStream_t stream) {
    const float* x    = (const float*)d_in[0];
    const float* wqkv = (const float*)d_in[1];
    const float* wout = (const float*)d_in[2];
    const float* bout = (const float*)d_in[3];
    float* out = (float*)d_out;

    char* w = (char*)d_ws;
    bf16_t* xb    = (bf16_t*)w; w += (size_t)MTOT*EDIM*2;     // 33.5 MB
    bf16_t* wqkvb = (bf16_t*)w; w += (size_t)3*EDIM*EDIM*2;   // 25.2 MB
    bf16_t* woutb = (bf16_t*)w; w += (size_t)EDIM*EDIM*2;     //  8.4 MB
    bf16_t* qbuf  = (bf16_t*)w; w += (size_t)MTOT*EDIM*2;     // 33.5 MB  [bh][s][d]
    bf16_t* kbuf  = (bf16_t*)w; w += (size_t)MTOT*EDIM*2;     // 33.5 MB  [bh][s][d]
    bf16_t* vbuf  = (bf16_t*)w; w += (size_t)MTOT*EDIM*2;     // 33.5 MB  [bh][d][s]
    bf16_t* attnb = (bf16_t*)w; w += (size_t)MTOT*EDIM*2;     // 33.5 MB  [b][s][e]

    cast_bf16_kernel<<<MTOT*EDIM/1024, 256, 0, stream>>>(x, xb, MTOT*EDIM/4);
    cast_bf16_kernel<<<3*EDIM*EDIM/1024, 256, 0, stream>>>(wqkv, wqkvb, 3*EDIM*EDIM/4);
    cast_bf16_kernel<<<EDIM*EDIM/1024, 256, 0, stream>>>(wout, woutb, EDIM*EDIM/4);

    gemm_nt<0><<<dim3((MTOT/256)*(3*EDIM/256)), 512, 0, stream>>>(
        xb, wqkvb, MTOT, 3*EDIM, EDIM, nullptr, nullptr, qbuf, kbuf, vbuf);

    attn_kernel<<<dim3(512), 512, 0, stream>>>(qbuf, kbuf, vbuf, attnb);

    gemm_nt<1><<<dim3((MTOT/256)*(EDIM/256)), 512, 0, stream>>>(
        attnb, woutb, MTOT, EDIM, EDIM, out, bout, nullptr, nullptr, nullptr);
}